// Round 9
// baseline (437.711 us; speedup 1.0000x reference)
//
#include <hip/hip_runtime.h>
#include <hip/hip_fp16.h>
#include <hip/hip_cooperative_groups.h>

namespace cg = cooperative_groups;

#define C 128
#define NEG_SLOPE 0.2f
#define SM_EPS 1e-16f
#define BKT_SHIFT 8            // 256 nodes per bucket
#define BKT_MASK 255
#define CHUNK 16384            // edges per hist/bin chunk (256 thr, 64/thread)
#define WP 136                 // LDS pitch (u16) for h-writeback slice
#define SMEM_SCRATCH 17408     // gemm slice = 4*16*136*2 B (largest phase)

typedef unsigned int uint32;
typedef __attribute__((ext_vector_type(8))) short bf16x8;
typedef __attribute__((ext_vector_type(4))) float f32x4;

// ---- bf16 helpers (RNE) ----
static __device__ __forceinline__ unsigned short f2bf(float f) {
    uint32 u = __float_as_uint(f);
    uint32 r = 0x7FFFu + ((u >> 16) & 1u);
    return (unsigned short)((u + r) >> 16);
}
static __device__ __forceinline__ uint32 f2bf2(float lo, float hi) {
    return (uint32)f2bf(lo) | ((uint32)f2bf(hi) << 16);
}
// ---- f16 bit helpers ----
static __device__ __forceinline__ uint32 f2h(float f) {
    __half h = __float2half(f);
    return (uint32)*reinterpret_cast<unsigned short*>(&h);
}
static __device__ __forceinline__ float h2f(uint32 b) {
    unsigned short s = (unsigned short)(b & 0xffffu);
    __half h = *reinterpret_cast<__half*>(&s);
    return __half2float(h);
}

struct GatParams {
    const float* x; const float* W; const float* a_src; const float* a_dst;
    const float* bias; const int* src; const int* dst;
    unsigned short* hb; float* as; float* ad;
    int* row_start; uint32* packed; uint32* csr; uint32* Wf;
    int* H; int* colTot; float* out;
    int N, E, total, NB, nchunk, ntile;
};

// 256-thread exclusive scan (wave scan + LDS wave totals). Two barriers.
static __device__ int scan256(int v, int tid, int* wt) {
    const int lane = tid & 63;
    const int w = tid >> 6;
    int x = v;
    #pragma unroll
    for (int o = 1; o < 64; o <<= 1) {
        int t = __shfl_up(x, o, 64);
        if (lane >= o) x += t;
    }
    if (lane == 63) wt[w] = x;
    __syncthreads();
    int wbase = 0;
    #pragma unroll
    for (int w2 = 0; w2 < 4; ++w2) wbase += (w2 < w) ? wt[w2] : 0;
    __syncthreads();
    return wbase + x - v;
}

// redundant per-block exclusive scan of colTot -> boff (LDS), sentinel at 256
static __device__ void make_boff(const int* colTot, int total, int tid,
                                 int* boff, int* wt) {
    int v = colTot[tid];
    int e = scan256(v, tid, wt);
    boff[tid] = e;
    if (tid == 0) boff[256] = total;
    __syncthreads();
}

// ---- phase A: W -> bf16 fragment order + per-chunk bucket histogram ----
static __device__ void phaseA(const GatParams& p, char* smem) {
    const int tid = threadIdx.x;
    int* lhist = (int*)smem;
    for (int g = blockIdx.x * 256 + tid; g < 8192; g += gridDim.x * 256) {
        int j2   = g & 3;
        int lane = (g >> 2) & 63;
        int tile = g >> 8;
        int t = tile >> 2, kk = tile & 3;
        int n = t * 16 + (lane & 15);
        int k = kk * 32 + (lane >> 4) * 8 + j2 * 2;
        p.Wf[g] = f2bf2(p.W[k * C + n], p.W[(k + 1) * C + n]);
    }
    for (int c = blockIdx.x; c < p.nchunk; c += gridDim.x) {
        lhist[tid] = 0;
        __syncthreads();
        const int start = c * CHUNK;
        const int end = min(start + CHUNK, p.total);
        for (int i = start + tid; i < end; i += 256) {
            int d = (i < p.E) ? p.dst[i] : (i - p.E);
            atomicAdd(&lhist[d >> BKT_SHIFT], 1);
        }
        __syncthreads();
        p.H[c * 256 + tid] = lhist[tid];
        __syncthreads();
    }
}

// ---- phase B: parallel column scan of H + bucket totals ----
static __device__ void phaseB(const GatParams& p, int* wt) {
    const int tid = threadIdx.x;
    for (int col = blockIdx.x; col < 256; col += gridDim.x) {
        int v = (tid < p.nchunk) ? p.H[tid * 256 + col] : 0;
        int e = scan256(v, tid, wt);
        if (tid < p.nchunk) p.H[tid * 256 + col] = e;
        if (tid == 255) p.colTot[col] = e + v;
        __syncthreads();
    }
}

// ---- GEMM tile (one 64-row tile, 256 threads) ----
static __device__ void gemm_tile(const GatParams& p, int tile, char* smem) {
    typedef unsigned short SliceT[16 * WP];
    SliceT* slice = (SliceT*)smem;
    const int tid  = threadIdx.x;
    const int lane = tid & 63;
    const int w    = tid >> 6;
    const int row0 = tile * 64;
    const int m16  = lane & 15;
    const int q    = lane >> 4;

    const int row = row0 + w * 16 + m16;
    const bool rv = (row < p.N);
    const float* xr_p = p.x + (size_t)(rv ? row : 0) * C + q * 8;

    float4 xr[8];
    #pragma unroll
    for (int kk = 0; kk < 4; ++kk) {
        xr[kk * 2]     = rv ? *(const float4*)(xr_p + kk * 32)     : make_float4(0, 0, 0, 0);
        xr[kk * 2 + 1] = rv ? *(const float4*)(xr_p + kk * 32 + 4) : make_float4(0, 0, 0, 0);
    }

    f32x4 acc[8];
    const f32x4 zz = {0.f, 0.f, 0.f, 0.f};
    #pragma unroll
    for (int t = 0; t < 8; ++t) acc[t] = zz;

    #pragma unroll
    for (int kk = 0; kk < 4; ++kk) {
        union { bf16x8 v; uint32 u[4]; } au;
        float4 p0 = xr[kk * 2], p1 = xr[kk * 2 + 1];
        au.u[0] = f2bf2(p0.x, p0.y); au.u[1] = f2bf2(p0.z, p0.w);
        au.u[2] = f2bf2(p1.x, p1.y); au.u[3] = f2bf2(p1.z, p1.w);
        #pragma unroll
        for (int t = 0; t < 8; ++t) {
            bf16x8 b = *(const bf16x8*)&p.Wf[((t * 4 + kk) * 64 + lane) * 4];
            acc[t] = __builtin_amdgcn_mfma_f32_16x16x32_bf16(au.v, b, acc[t], 0, 0, 0);
        }
    }

    float ps[4] = {0.f, 0.f, 0.f, 0.f}, pd[4] = {0.f, 0.f, 0.f, 0.f};
    #pragma unroll
    for (int t = 0; t < 8; ++t) {
        float av = p.a_src[t * 16 + m16];
        float dv = p.a_dst[t * 16 + m16];
        #pragma unroll
        for (int r = 0; r < 4; ++r) {
            ps[r] += acc[t][r] * av;
            pd[r] += acc[t][r] * dv;
        }
    }
    #pragma unroll
    for (int r = 0; r < 4; ++r) {
        #pragma unroll
        for (int off = 1; off < 16; off <<= 1) {
            ps[r] += __shfl_xor(ps[r], off, 64);
            pd[r] += __shfl_xor(pd[r], off, 64);
        }
    }
    if (m16 == 0) {
        #pragma unroll
        for (int r = 0; r < 4; ++r) {
            int rr = row0 + w * 16 + q * 4 + r;
            if (rr < p.N) { p.as[rr] = ps[r]; p.ad[rr] = pd[r]; }
        }
    }

    #pragma unroll
    for (int t = 0; t < 8; ++t)
        #pragma unroll
        for (int r = 0; r < 4; ++r)
            slice[w][(q * 4 + r) * WP + t * 16 + m16] = f2bf(acc[t][r]);
    __syncthreads();
    #pragma unroll
    for (int it = 0; it < 4; ++it) {
        int r = it * 4 + q;
        int rr = row0 + w * 16 + r;
        if (rr < p.N) {
            bf16x8 v = *(const bf16x8*)&slice[w][r * WP + m16 * 8];
            *(bf16x8*)&p.hb[(size_t)rr * C + m16 * 8] = v;
        }
    }
}

// ---- bin chunk (deterministic bases, LDS-only atomics, 256 threads) ----
static __device__ void bin_chunk(const GatParams& p, int c, char* smem,
                                 const int* boff) {
    const int tid = threadIdx.x;
    int* lhist = (int*)smem;
    int* base  = lhist + 256;
    lhist[tid] = 0;
    __syncthreads();
    const int start = c * CHUNK;
    const int end = min(start + CHUNK, p.total);
    for (int i = start + tid; i < end; i += 256) {
        int d = (i < p.E) ? p.dst[i] : (i - p.E);
        atomicAdd(&lhist[d >> BKT_SHIFT], 1);
    }
    __syncthreads();
    base[tid] = boff[tid] + p.H[c * 256 + tid];
    lhist[tid] = 0;
    __syncthreads();
    for (int i = start + tid; i < end; i += 256) {
        int s = (i < p.E) ? p.src[i] : (i - p.E);
        int d = (i < p.E) ? p.dst[i] : (i - p.E);
        int b = d >> BKT_SHIFT;
        int pos = base[b] + atomicAdd(&lhist[b], 1);
        p.packed[pos] = ((uint32)s << BKT_SHIFT) | (uint32)(d & BKT_MASK);
    }
}

// ---- phase C: GEMM blocks || bin blocks (independent, overlap on CUs) ----
static __device__ void phaseC(const GatParams& p, char* smem, int* boff, int* wt) {
    make_boff(p.colTot, p.total, threadIdx.x, boff, wt);
    const int nrole = p.ntile + p.nchunk;
    for (int r = blockIdx.x; r < nrole; r += gridDim.x) {
        if (r < p.ntile) gemm_tile(p, r, smem);
        else             bin_chunk(p, r - p.ntile, smem, boff);
        __syncthreads();
    }
}

// ---- phase D: build (per-bucket fine sort + fused e), 256 threads ----
static __device__ void phaseD(const GatParams& p, char* smem, int* boff, int* wt) {
    make_boff(p.colTot, p.total, threadIdx.x, boff, wt);
    const int tid = threadIdx.x;
    if (blockIdx.x == 0 && tid == 0) p.row_start[p.N] = p.total;
    int* cnt = (int*)smem;
    int* cur = cnt + 256;
    float* adl = (float*)(cur + 256);
    for (int b = blockIdx.x; b < p.NB; b += gridDim.x) {
        cnt[tid] = 0;
        const int g = (b << BKT_SHIFT) + tid;
        adl[tid] = (g < p.N) ? p.ad[g] : 0.f;
        __syncthreads();
        const int off = boff[b];
        const int end = boff[b + 1];
        for (int j = off + tid; j < end; j += 256)
            atomicAdd(&cnt[p.packed[j] & BKT_MASK], 1);
        __syncthreads();
        int v2 = cnt[tid];
        int excl = scan256(v2, tid, wt);
        if (g < p.N) p.row_start[g] = off + excl;
        cur[tid] = excl;
        __syncthreads();
        for (int j = off + tid; j < end; j += 256) {
            uint32 pk = p.packed[j];
            int l = (int)(pk & BKT_MASK);
            int s = (int)(pk >> BKT_SHIFT);
            float e = p.as[s] + adl[l];
            e = (e > 0.f) ? e : NEG_SLOPE * e;
            int pos = atomicAdd(&cur[l], 1);
            p.csr[off + pos] = ((uint32)s << 16) | f2h(e);
        }
        __syncthreads();
    }
}

// ---- full-wave fallback for deg>64 nodes ----
static __device__ void gather_node_fw(
    const GatParams& p, int d, int lane)
{
    const int beg = p.row_start[d];
    const int deg = p.row_start[d + 1] - beg;
    const int c2 = lane << 1;
    float a0 = 0.f, a1 = 0.f;
    float m = -INFINITY;
    for (int t = lane; t < deg; t += 64) m = fmaxf(m, h2f(p.csr[beg + t]));
    #pragma unroll
    for (int off = 32; off > 0; off >>= 1) m = fmaxf(m, __shfl_xor(m, off, 64));
    float ssum = 0.f;
    for (int t = lane; t < deg; t += 64) ssum += __expf(h2f(p.csr[beg + t]) - m);
    #pragma unroll
    for (int off = 32; off > 0; off >>= 1) ssum += __shfl_xor(ssum, off, 64);
    float inv = 1.f / (ssum + SM_EPS);
    for (int t0 = 0; t0 < deg; t0 += 64) {
        int nc = min(64, deg - t0);
        uint32 ent = (lane < nc) ? p.csr[beg + t0 + lane] : 0xFC00u;
        float wl = (lane < nc) ? __expf(h2f(ent) - m) * inv : 0.f;
        uint32 bc = (ent & 0xffff0000u) | f2h(wl);
        for (int t = 0; t < nc; ++t) {
            uint32 b0 = (uint32)__shfl((int)bc, t, 64);
            uint32 u0 = *(const uint32*)&p.hb[(size_t)(b0 >> 16) * C + c2];
            float w0 = h2f(b0);
            a0 += __uint_as_float(u0 << 16) * w0;
            a1 += __uint_as_float(u0 & 0xffff0000u) * w0;
        }
    }
    float2 b2 = *(const float2*)&p.bias[c2];
    a0 = fmaxf(a0 + b2.x, 0.f);
    a1 = fmaxf(a1 + b2.y, 0.f);
    *(float2*)&p.out[(size_t)d * C + c2] = make_float2(a0, a1);
}

#define ACC4(r, wgt)                                           \
    {                                                          \
        a0 += __uint_as_float((r).x << 16)         * (wgt);    \
        a1 += __uint_as_float((r).x & 0xffff0000u) * (wgt);    \
        a2 += __uint_as_float((r).y << 16)         * (wgt);    \
        a3 += __uint_as_float((r).y & 0xffff0000u) * (wgt);    \
    }

// ---- gather pair: 2 dst nodes per wave (half-wave each), MLP=8 ----
static __device__ void gather_pair(const GatParams& p, int pair, uint2* lw,
                                   int lane)
{
    const int half = lane >> 5;
    const int hl   = lane & 31;
    const int d0 = pair * 2;
    const int d = d0 + half;
    const bool valid = (d < p.N);

    int beg = 0, deg = 0;
    if (valid) { beg = p.row_start[d]; deg = p.row_start[d + 1] - beg; }

    int wdeg = deg;
    #pragma unroll
    for (int off = 32; off > 0; off >>= 1) wdeg = max(wdeg, __shfl_xor(wdeg, off, 64));

    if (wdeg > 64) {
        gather_node_fw(p, d0, lane);
        if (d0 + 1 < p.N) gather_node_fw(p, d0 + 1, lane);
        return;
    }

    uint32 ent0 = (hl < deg) ? p.csr[beg + hl] : 0xFC00u;
    uint32 ent1 = (32 + hl < deg) ? p.csr[beg + 32 + hl] : 0xFC00u;
    float e0 = h2f(ent0), e1 = h2f(ent1);
    float m = fmaxf(e0, e1);
    #pragma unroll
    for (int off = 16; off > 0; off >>= 1) m = fmaxf(m, __shfl_xor(m, off, 64));
    float p0 = (hl < deg) ? __expf(e0 - m) : 0.f;
    float p1 = (32 + hl < deg) ? __expf(e1 - m) : 0.f;
    float ssum = p0 + p1;
    #pragma unroll
    for (int off = 16; off > 0; off >>= 1) ssum += __shfl_xor(ssum, off, 64);
    const float inv = 1.f / (ssum + SM_EPS);

    lw[half * 64 + hl]      = make_uint2((ent0 & 0xffff0000u) >> 8, __float_as_uint(p0 * inv));
    lw[half * 64 + 32 + hl] = make_uint2((ent1 & 0xffff0000u) >> 8, __float_as_uint(p1 * inv));
    __builtin_amdgcn_wave_barrier();

    const uint32 cb = (uint32)(hl << 3);
    const char* hbB = (const char*)p.hb;
    const uint2* lp = lw + half * 64;
    float a0 = 0.f, a1 = 0.f, a2 = 0.f, a3 = 0.f;

    int t = 0;
    for (; t + 8 <= deg; t += 8) {
        uint4 q0 = *(const uint4*)(lp + t);
        uint4 q1 = *(const uint4*)(lp + t + 2);
        uint4 q2 = *(const uint4*)(lp + t + 4);
        uint4 q3 = *(const uint4*)(lp + t + 6);
        uint2 r0 = *(const uint2*)(hbB + (q0.x + cb));
        uint2 r1 = *(const uint2*)(hbB + (q0.z + cb));
        uint2 r2 = *(const uint2*)(hbB + (q1.x + cb));
        uint2 r3 = *(const uint2*)(hbB + (q1.z + cb));
        uint2 r4 = *(const uint2*)(hbB + (q2.x + cb));
        uint2 r5 = *(const uint2*)(hbB + (q2.z + cb));
        uint2 r6 = *(const uint2*)(hbB + (q3.x + cb));
        uint2 r7 = *(const uint2*)(hbB + (q3.z + cb));
        float w0 = __uint_as_float(q0.y), w1 = __uint_as_float(q0.w);
        float w2 = __uint_as_float(q1.y), w3 = __uint_as_float(q1.w);
        float w4 = __uint_as_float(q2.y), w5 = __uint_as_float(q2.w);
        float w6 = __uint_as_float(q3.y), w7 = __uint_as_float(q3.w);
        ACC4(r0, w0) ACC4(r1, w1) ACC4(r2, w2) ACC4(r3, w3)
        ACC4(r4, w4) ACC4(r5, w5) ACC4(r6, w6) ACC4(r7, w7)
    }
    for (; t < deg; ++t) {
        uint2 qv = lp[t];
        uint2 r = *(const uint2*)(hbB + (qv.x + cb));
        float wt = __uint_as_float(qv.y);
        ACC4(r, wt)
    }

    if (valid) {
        const int c4 = hl << 2;
        float4 bb = *(const float4*)&p.bias[c4];
        float4 o;
        o.x = fmaxf(a0 + bb.x, 0.f);
        o.y = fmaxf(a1 + bb.y, 0.f);
        o.z = fmaxf(a2 + bb.z, 0.f);
        o.w = fmaxf(a3 + bb.w, 0.f);
        *(float4*)&p.out[(size_t)d * C + c4] = o;
    }
}

// ---- phase E: gather, grid-strided over node pairs ----
static __device__ void phaseE(const GatParams& p, char* smem) {
    const int w = threadIdx.x >> 6;
    const int lane = threadIdx.x & 63;
    uint2* lw = (uint2*)smem + w * 128;
    const int P = (p.N + 1) >> 1;
    for (int pair = blockIdx.x * 4 + w; pair < P; pair += gridDim.x * 4)
        gather_pair(p, pair, lw, lane);
}

// ---- mega kernel (cooperative): all phases, grid sync between ----
__global__ __launch_bounds__(256) void mega_kernel(GatParams p) {
    __shared__ __align__(16) char smem[SMEM_SCRATCH + 257 * 4 + 32];
    int* boff = (int*)(smem + SMEM_SCRATCH);
    int* wt   = boff + 257;
    cg::grid_group gg = cg::this_grid();
    phaseA(p, smem);
    gg.sync();
    phaseB(p, wt);
    gg.sync();
    phaseC(p, smem, boff, wt);
    gg.sync();
    phaseD(p, smem, boff, wt);
    gg.sync();
    phaseE(p, smem);
}

// ---- fallback: same phases as 5 normal launches ----
__global__ __launch_bounds__(256) void phase_kernel(GatParams p, int phase) {
    __shared__ __align__(16) char smem[SMEM_SCRATCH + 257 * 4 + 32];
    int* boff = (int*)(smem + SMEM_SCRATCH);
    int* wt   = boff + 257;
    if      (phase == 0) phaseA(p, smem);
    else if (phase == 1) phaseB(p, wt);
    else if (phase == 2) phaseC(p, smem, boff, wt);
    else if (phase == 3) phaseD(p, smem, boff, wt);
    else                 phaseE(p, smem);
}

extern "C" void kernel_launch(void* const* d_in, const int* in_sizes, int n_in,
                              void* d_out, int out_size, void* d_ws, size_t ws_size,
                              hipStream_t stream) {
    const float* x     = (const float*)d_in[0];
    const float* W     = (const float*)d_in[1];
    const float* a_src = (const float*)d_in[2];
    const float* a_dst = (const float*)d_in[3];
    const float* bias  = (const float*)d_in[4];
    const int*   edge  = (const int*)d_in[5];

    const int N = in_sizes[0] / C;
    const int E = in_sizes[5] / 2;
    const int total = E + N;

    GatParams p;
    p.x = x; p.W = W; p.a_src = a_src; p.a_dst = a_dst; p.bias = bias;
    p.src = edge; p.dst = edge + E;
    p.out = (float*)d_out;
    p.N = N; p.E = E; p.total = total;
    p.NB = (N + BKT_MASK) >> BKT_SHIFT;
    p.nchunk = (total + CHUNK - 1) / CHUNK;
    p.ntile = (N + 63) / 64;

    // workspace (4B units): hb[N*C/2] | as[N] | ad[N] | row_start[N+2]
    // | packed[total] | csr[total] | Wf[8192] | colTot[256] | H[nchunk*256]
    float* ws = (float*)d_ws;
    p.hb = (unsigned short*)ws;
    p.as = (float*)(p.hb + (size_t)N * C);
    p.ad = p.as + N;
    p.row_start = (int*)(p.ad + N);
    p.packed = (uint32*)(p.row_start + (N + 2));
    p.csr = p.packed + total;
    p.Wf = p.csr + total;
    p.colTot = (int*)(p.Wf + 8192);
    p.H = p.colTot + 256;

    static int G = 0, coop = 0;
    if (G == 0) {
        int dev = 0;
        hipGetDevice(&dev);
        int nCU = 0;
        hipDeviceGetAttribute(&nCU, hipDeviceAttributeMultiprocessorCount, dev);
        hipDeviceGetAttribute(&coop, hipDeviceAttributeCooperativeLaunch, dev);
        int bpc = 0;
        hipOccupancyMaxActiveBlocksPerMultiprocessor(
            &bpc, (const void*)mega_kernel, 256, 0);
        if (bpc < 1) { bpc = 1; }
        if (nCU < 1) { nCU = 256; }
        G = nCU * bpc;
        if (G > 2048) G = 2048;
        if (G < 256)  G = 256;
    }

    bool launched = false;
    if (coop) {
        GatParams pl = p;
        void* args[] = { (void*)&pl };
        hipError_t err = hipLaunchCooperativeKernel(
            (const void*)mega_kernel, dim3(G), dim3(256), args, 0, stream);
        launched = (err == hipSuccess);
    }
    if (!launched) {
        const int gA = (p.nchunk > 32) ? p.nchunk : 32;
        const int gC = p.ntile + p.nchunk;
        const int gE = (((N + 1) >> 1) + 3) / 4;
        phase_kernel<<<gA, 256, 0, stream>>>(p, 0);
        phase_kernel<<<256, 256, 0, stream>>>(p, 1);
        phase_kernel<<<gC, 256, 0, stream>>>(p, 2);
        phase_kernel<<<p.NB, 256, 0, stream>>>(p, 3);
        phase_kernel<<<gE, 256, 0, stream>>>(p, 4);
    }
}

// Round 10
// 187.639 us; speedup vs baseline: 2.3327x; 2.3327x over previous
//
#include <hip/hip_runtime.h>
#include <hip/hip_fp16.h>

#define C 128
#define NEG_SLOPE 0.2f
#define SM_EPS 1e-16f
#define BKT_SHIFT 8            // 256 nodes per bucket
#define BKT_MASK 255
#define WP 136                 // LDS pitch (u16) for h-writeback slice

typedef unsigned int uint32;
typedef __attribute__((ext_vector_type(8))) short bf16x8;
typedef __attribute__((ext_vector_type(4))) float f32x4;

// ---- bf16 helpers (RNE) ----
static __device__ __forceinline__ unsigned short f2bf(float f) {
    uint32 u = __float_as_uint(f);
    uint32 r = 0x7FFFu + ((u >> 16) & 1u);
    return (unsigned short)((u + r) >> 16);
}
static __device__ __forceinline__ uint32 f2bf2(float lo, float hi) {
    return (uint32)f2bf(lo) | ((uint32)f2bf(hi) << 16);
}
// ---- f16 bit helpers ----
static __device__ __forceinline__ uint32 f2h(float f) {
    __half h = __float2half(f);
    return (uint32)*reinterpret_cast<unsigned short*>(&h);
}
static __device__ __forceinline__ float h2f(uint32 b) {
    unsigned short s = (unsigned short)(b & 0xffffu);
    __half h = *reinterpret_cast<__half*>(&s);
    return __half2float(h);
}

// ---- k0: W -> bf16 fragment-ordered ----
__global__ __launch_bounds__(256) void cvtw_kernel(const float* __restrict__ W,
                                                   uint32* __restrict__ Wf) {
    int gid = blockIdx.x * 256 + threadIdx.x;       // 0..8191
    int j2   = gid & 3;
    int lane = (gid >> 2) & 63;
    int tile = gid >> 8;                            // t*4+kk
    int t = tile >> 2, kk = tile & 3;
    int n = t * 16 + (lane & 15);
    int k = kk * 32 + (lane >> 4) * 8 + j2 * 2;
    Wf[gid] = f2bf2(W[k * C + n], W[(k + 1) * C + n]);
}

// ---- k1: MFMA GEMM + alpha reductions + bf16 h + per-chunk hist row ----
// block c: GEMM rows [c*64, c*64+64) AND histogram of edge chunk c into H[c][256].
__global__ __launch_bounds__(256) void gemm_hist_kernel(
    const float* __restrict__ x, const uint32* __restrict__ Wf,
    const float* __restrict__ a_src, const float* __restrict__ a_dst,
    unsigned short* __restrict__ hb, float* __restrict__ as_out,
    float* __restrict__ ad_out, int N,
    const int* __restrict__ dst, int* __restrict__ H,
    int E, int total, int chunkE)
{
    __shared__ __align__(16) unsigned short slice[4][16 * WP];
    __shared__ int lhist[256];

    const int tid  = threadIdx.x;
    const int lane = tid & 63;
    const int w    = tid >> 6;
    const int row0 = blockIdx.x * 64;
    const int m16  = lane & 15;
    const int q    = lane >> 4;

    lhist[tid] = 0;

    const int row = row0 + w * 16 + m16;
    const bool rv = (row < N);
    const float* xr_p = x + (size_t)(rv ? row : 0) * C + q * 8;

    float4 xr[8];
    #pragma unroll
    for (int kk = 0; kk < 4; ++kk) {
        xr[kk * 2]     = rv ? *(const float4*)(xr_p + kk * 32)     : make_float4(0, 0, 0, 0);
        xr[kk * 2 + 1] = rv ? *(const float4*)(xr_p + kk * 32 + 4) : make_float4(0, 0, 0, 0);
    }

    f32x4 acc[8];
    const f32x4 zz = {0.f, 0.f, 0.f, 0.f};
    #pragma unroll
    for (int t = 0; t < 8; ++t) acc[t] = zz;

    #pragma unroll
    for (int kk = 0; kk < 4; ++kk) {
        union { bf16x8 v; uint32 u[4]; } au;
        float4 p0 = xr[kk * 2], p1 = xr[kk * 2 + 1];
        au.u[0] = f2bf2(p0.x, p0.y); au.u[1] = f2bf2(p0.z, p0.w);
        au.u[2] = f2bf2(p1.x, p1.y); au.u[3] = f2bf2(p1.z, p1.w);
        #pragma unroll
        for (int t = 0; t < 8; ++t) {
            bf16x8 b = *(const bf16x8*)&Wf[((t * 4 + kk) * 64 + lane) * 4];
            acc[t] = __builtin_amdgcn_mfma_f32_16x16x32_bf16(au.v, b, acc[t], 0, 0, 0);
        }
    }

    float ps[4] = {0.f, 0.f, 0.f, 0.f}, pd[4] = {0.f, 0.f, 0.f, 0.f};
    #pragma unroll
    for (int t = 0; t < 8; ++t) {
        float av = a_src[t * 16 + m16];
        float dv = a_dst[t * 16 + m16];
        #pragma unroll
        for (int r = 0; r < 4; ++r) {
            ps[r] += acc[t][r] * av;
            pd[r] += acc[t][r] * dv;
        }
    }
    #pragma unroll
    for (int r = 0; r < 4; ++r) {
        #pragma unroll
        for (int off = 1; off < 16; off <<= 1) {
            ps[r] += __shfl_xor(ps[r], off, 64);
            pd[r] += __shfl_xor(pd[r], off, 64);
        }
    }
    if (m16 == 0) {
        #pragma unroll
        for (int r = 0; r < 4; ++r) {
            int rr = row0 + w * 16 + q * 4 + r;
            if (rr < N) { as_out[rr] = ps[r]; ad_out[rr] = pd[r]; }
        }
    }

    #pragma unroll
    for (int t = 0; t < 8; ++t)
        #pragma unroll
        for (int r = 0; r < 4; ++r)
            slice[w][(q * 4 + r) * WP + t * 16 + m16] = f2bf(acc[t][r]);
    __syncthreads();
    #pragma unroll
    for (int it = 0; it < 4; ++it) {
        int r = it * 4 + q;
        int rr = row0 + w * 16 + r;
        if (rr < N) {
            bf16x8 v = *(const bf16x8*)&slice[w][r * WP + m16 * 8];
            *(bf16x8*)&hb[(size_t)rr * C + m16 * 8] = v;
        }
    }

    // per-chunk histogram (chunk = blockIdx), LDS-only, plain store to H row
    const int c = blockIdx.x;
    const int start = c * chunkE;
    const int end = min(start + chunkE, total);
    for (int i = start + tid; i < end; i += 256) {
        int d = (i < E) ? dst[i] : (i - E);
        atomicAdd(&lhist[d >> BKT_SHIFT], 1);
    }
    __syncthreads();
    H[c * 256 + tid] = lhist[tid];
}

// ---- k2: parallel column scan of H (one column per block) ----
// H[c][b] -> exclusive per-chunk base within bucket b; colTot[b] = bucket total.
__global__ __launch_bounds__(1024) void scan_cols_kernel(
    int* __restrict__ H, int* __restrict__ colTot, int nchunk)
{
    __shared__ int wt[16];
    const int tid  = threadIdx.x;
    const int lane = tid & 63;
    const int w    = tid >> 6;
    const int col  = blockIdx.x;
    int v = (tid < nchunk) ? H[tid * 256 + col] : 0;
    int x = v;
    #pragma unroll
    for (int o = 1; o < 64; o <<= 1) {
        int t = __shfl_up(x, o, 64);
        if (lane >= o) x += t;
    }
    if (lane == 63) wt[w] = x;
    __syncthreads();
    int wbase = 0;
    #pragma unroll
    for (int w2 = 0; w2 < 16; ++w2) wbase += (w2 < w) ? wt[w2] : 0;
    int e = wbase + x - v;
    if (tid < nchunk) H[tid * 256 + col] = e;
    if (tid == nchunk - 1) colTot[col] = e + v;
}

// ---- k2.5: one-block scan of colTot -> bucket_off (+sentinel) ----
__global__ __launch_bounds__(256) void scan_off_kernel(
    const int* __restrict__ colTot, int* __restrict__ bucket_off, int total)
{
    __shared__ int wt[4];
    const int tid = threadIdx.x;
    const int lane = tid & 63;
    const int w = tid >> 6;
    int v = colTot[tid];
    int x = v;
    #pragma unroll
    for (int o = 1; o < 64; o <<= 1) {
        int t = __shfl_up(x, o, 64);
        if (lane >= o) x += t;
    }
    if (lane == 63) wt[w] = x;
    __syncthreads();
    int wbase = 0;
    #pragma unroll
    for (int w2 = 0; w2 < 4; ++w2) wbase += (w2 < w) ? wt[w2] : 0;
    bucket_off[tid] = wbase + x - v;
    if (tid == 0) bucket_off[256] = total;
}

// ---- k3: bin, deterministic bases (zero global atomics), re-read variant ----
__global__ __launch_bounds__(256) void bin_kernel(
    const int* __restrict__ src, const int* __restrict__ dst,
    const int* __restrict__ bucket_off, const int* __restrict__ H,
    uint32* __restrict__ packed, int E, int total, int chunkE)
{
    __shared__ int lhist[256];
    __shared__ int base[256];
    const int tid = threadIdx.x;
    const int c = blockIdx.x;
    const int start = c * chunkE;
    const int end = min(start + chunkE, total);

    lhist[tid] = 0;
    __syncthreads();
    for (int i = start + tid; i < end; i += 256) {
        int d = (i < E) ? dst[i] : (i - E);
        atomicAdd(&lhist[d >> BKT_SHIFT], 1);
    }
    __syncthreads();
    base[tid] = bucket_off[tid] + H[c * 256 + tid];
    lhist[tid] = 0;
    __syncthreads();
    for (int i = start + tid; i < end; i += 256) {
        int s = (i < E) ? src[i] : (i - E);
        int d = (i < E) ? dst[i] : (i - E);
        int b = d >> BKT_SHIFT;
        int pos = base[b] + atomicAdd(&lhist[b], 1);
        packed[pos] = ((uint32)s << BKT_SHIFT) | (uint32)(d & BKT_MASK);
    }
}

// ---- k4: build, per-bucket fine sort + fused e (straight-line barriers) ----
__global__ __launch_bounds__(1024) void build_kernel(
    const uint32* __restrict__ packed, const int* __restrict__ bucket_off,
    const float* __restrict__ as, const float* __restrict__ ad,
    int* __restrict__ row_start, uint32* __restrict__ csr, int N, int NB, int total)
{
    __shared__ int cnt[256];
    __shared__ int cur[256];
    __shared__ float adl[256];
    __shared__ int wt[4];
    const int tid = threadIdx.x;
    const int b = blockIdx.x;

    if (tid < 256) {
        cnt[tid] = 0;
        int g = (b << BKT_SHIFT) + tid;
        adl[tid] = (g < N) ? ad[g] : 0.f;
    }
    __syncthreads();
    const int off = bucket_off[b];
    const int end = bucket_off[b + 1];
    if (b == 0 && tid == 0) row_start[N] = total;

    for (int j = off + tid; j < end; j += 1024)
        atomicAdd(&cnt[packed[j] & BKT_MASK], 1);
    __syncthreads();

    int v2 = 0, x2 = 0;
    if (tid < 256) {
        const int lane = tid & 63;
        v2 = cnt[tid]; x2 = v2;
        #pragma unroll
        for (int o = 1; o < 64; o <<= 1) {
            int t = __shfl_up(x2, o, 64);
            if (lane >= o) x2 += t;
        }
        if (lane == 63) wt[tid >> 6] = x2;
    }
    __syncthreads();
    if (tid < 256) {
        const int w = tid >> 6;
        int wbase = 0;
        #pragma unroll
        for (int w2 = 0; w2 < 4; ++w2) wbase += (w2 < w) ? wt[w2] : 0;
        int excl = wbase + x2 - v2;
        int g = (b << BKT_SHIFT) + tid;
        if (g < N) row_start[g] = off + excl;
        cur[tid] = excl;
    }
    __syncthreads();

    for (int j = off + tid; j < end; j += 1024) {
        uint32 p = packed[j];
        int l = (int)(p & BKT_MASK);
        int s = (int)(p >> BKT_SHIFT);
        float e = as[s] + adl[l];
        e = (e > 0.f) ? e : NEG_SLOPE * e;
        int pos = atomicAdd(&cur[l], 1);
        csr[off + pos] = ((uint32)s << 16) | f2h(e);
    }
}

// ---- full-wave fallback for deg>64 nodes ----
static __device__ __forceinline__ void gather_node_fw(
    int d, const uint32* __restrict__ csr, const int* __restrict__ row_start,
    const unsigned short* __restrict__ hb, const float* __restrict__ bias,
    float* __restrict__ out, int lane)
{
    const int beg = row_start[d];
    const int deg = row_start[d + 1] - beg;
    const int c2 = lane << 1;
    float a0 = 0.f, a1 = 0.f;
    float m = -INFINITY;
    for (int t = lane; t < deg; t += 64) m = fmaxf(m, h2f(csr[beg + t]));
    #pragma unroll
    for (int off = 32; off > 0; off >>= 1) m = fmaxf(m, __shfl_xor(m, off, 64));
    float ssum = 0.f;
    for (int t = lane; t < deg; t += 64) ssum += __expf(h2f(csr[beg + t]) - m);
    #pragma unroll
    for (int off = 32; off > 0; off >>= 1) ssum += __shfl_xor(ssum, off, 64);
    float inv = 1.f / (ssum + SM_EPS);
    for (int t0 = 0; t0 < deg; t0 += 64) {
        int nc = min(64, deg - t0);
        uint32 ent = (lane < nc) ? csr[beg + t0 + lane] : 0xFC00u;
        float wl = (lane < nc) ? __expf(h2f(ent) - m) * inv : 0.f;
        uint32 bc = (ent & 0xffff0000u) | f2h(wl);
        for (int t = 0; t < nc; ++t) {
            uint32 b0 = (uint32)__shfl((int)bc, t, 64);
            uint32 u0 = *(const uint32*)&hb[(size_t)(b0 >> 16) * C + c2];
            float w0 = h2f(b0);
            a0 += __uint_as_float(u0 << 16) * w0;
            a1 += __uint_as_float(u0 & 0xffff0000u) * w0;
        }
    }
    float2 b2 = *(const float2*)&bias[c2];
    a0 = fmaxf(a0 + b2.x, 0.f);
    a1 = fmaxf(a1 + b2.y, 0.f);
    *(float2*)&out[(size_t)d * C + c2] = make_float2(a0, a1);
}

// per-edge unpack+FMA on a loaded uint2 row fragment (4 bf16 channels)
#define ACC4(r, wgt)                                           \
    {                                                          \
        a0 += __uint_as_float((r).x << 16)         * (wgt);    \
        a1 += __uint_as_float((r).x & 0xffff0000u) * (wgt);    \
        a2 += __uint_as_float((r).y << 16)         * (wgt);    \
        a3 += __uint_as_float((r).y & 0xffff0000u) * (wgt);    \
    }

// ---- k5: half-wave gather: 2 dst nodes per wave, 4 ch/lane, MLP=8 ----
__global__ __launch_bounds__(256) void gather_kernel(
    const uint32* __restrict__ csr, const int* __restrict__ row_start,
    const unsigned short* __restrict__ hb, const float* __restrict__ bias,
    float* __restrict__ out, int N)
{
    __shared__ __align__(16) uint2 lent[4][2][64];   // 4 KB: per-wave, per-half
    const int w    = threadIdx.x >> 6;
    const int lane = threadIdx.x & 63;
    const int half = lane >> 5;
    const int hl   = lane & 31;
    const int pair = blockIdx.x * 4 + w;
    const int d0 = pair * 2;
    if (d0 >= N) return;                    // no barriers below: safe
    const int d = d0 + half;
    const bool valid = (d < N);

    int beg = 0, deg = 0;
    if (valid) { beg = row_start[d]; deg = row_start[d + 1] - beg; }

    int wdeg = deg;
    #pragma unroll
    for (int off = 32; off > 0; off >>= 1) wdeg = max(wdeg, __shfl_xor(wdeg, off, 64));

    if (wdeg > 64) {
        gather_node_fw(d0, csr, row_start, hb, bias, out, lane);
        if (d0 + 1 < N) gather_node_fw(d0 + 1, csr, row_start, hb, bias, out, lane);
        return;
    }

    uint32 ent0 = (hl < deg) ? csr[beg + hl] : 0xFC00u;
    uint32 ent1 = (32 + hl < deg) ? csr[beg + 32 + hl] : 0xFC00u;
    float e0 = h2f(ent0), e1 = h2f(ent1);
    float m = fmaxf(e0, e1);
    #pragma unroll
    for (int off = 16; off > 0; off >>= 1) m = fmaxf(m, __shfl_xor(m, off, 64));
    float p0 = (hl < deg) ? __expf(e0 - m) : 0.f;
    float p1 = (32 + hl < deg) ? __expf(e1 - m) : 0.f;
    float ssum = p0 + p1;
    #pragma unroll
    for (int off = 16; off > 0; off >>= 1) ssum += __shfl_xor(ssum, off, 64);
    const float inv = 1.f / (ssum + SM_EPS);

    // stage {row byte offset = src*256, f32 weight} — wave-synchronous LDS
    lent[w][half][hl]      = make_uint2((ent0 & 0xffff0000u) >> 8, __float_as_uint(p0 * inv));
    lent[w][half][32 + hl] = make_uint2((ent1 & 0xffff0000u) >> 8, __float_as_uint(p1 * inv));
    __builtin_amdgcn_wave_barrier();        // keep writes before reads (same wave)

    const uint32 cb = (uint32)(hl << 3);    // this lane's channel byte offset
    const char* hbB = (const char*)hb;
    const uint2* lp = &lent[w][half][0];
    float a0 = 0.f, a1 = 0.f, a2 = 0.f, a3 = 0.f;

    int t = 0;
    for (; t + 8 <= deg; t += 8) {
        uint4 q0 = *(const uint4*)(lp + t);
        uint4 q1 = *(const uint4*)(lp + t + 2);
        uint4 q2 = *(const uint4*)(lp + t + 4);
        uint4 q3 = *(const uint4*)(lp + t + 6);
        uint2 r0 = *(const uint2*)(hbB + (q0.x + cb));
        uint2 r1 = *(const uint2*)(hbB + (q0.z + cb));
        uint2 r2 = *(const uint2*)(hbB + (q1.x + cb));
        uint2 r3 = *(const uint2*)(hbB + (q1.z + cb));
        uint2 r4 = *(const uint2*)(hbB + (q2.x + cb));
        uint2 r5 = *(const uint2*)(hbB + (q2.z + cb));
        uint2 r6 = *(const uint2*)(hbB + (q3.x + cb));
        uint2 r7 = *(const uint2*)(hbB + (q3.z + cb));
        float w0 = __uint_as_float(q0.y), w1 = __uint_as_float(q0.w);
        float w2 = __uint_as_float(q1.y), w3 = __uint_as_float(q1.w);
        float w4 = __uint_as_float(q2.y), w5 = __uint_as_float(q2.w);
        float w6 = __uint_as_float(q3.y), w7 = __uint_as_float(q3.w);
        ACC4(r0, w0) ACC4(r1, w1) ACC4(r2, w2) ACC4(r3, w3)
        ACC4(r4, w4) ACC4(r5, w5) ACC4(r6, w6) ACC4(r7, w7)
    }
    for (; t < deg; ++t) {
        uint2 q = lp[t];
        uint2 r = *(const uint2*)(hbB + (q.x + cb));
        float wt = __uint_as_float(q.y);
        ACC4(r, wt)
    }

    if (valid) {
        const int c4 = hl << 2;
        float4 bb = *(const float4*)&bias[c4];
        float4 o;
        o.x = fmaxf(a0 + bb.x, 0.f);
        o.y = fmaxf(a1 + bb.y, 0.f);
        o.z = fmaxf(a2 + bb.z, 0.f);
        o.w = fmaxf(a3 + bb.w, 0.f);
        *(float4*)&out[(size_t)d * C + c4] = o;
    }
}

extern "C" void kernel_launch(void* const* d_in, const int* in_sizes, int n_in,
                              void* d_out, int out_size, void* d_ws, size_t ws_size,
                              hipStream_t stream) {
    const float* x     = (const float*)d_in[0];
    const float* W     = (const float*)d_in[1];
    const float* a_src = (const float*)d_in[2];
    const float* a_dst = (const float*)d_in[3];
    const float* bias  = (const float*)d_in[4];
    const int*   edge  = (const int*)d_in[5];

    const int N = in_sizes[0] / C;
    const int E = in_sizes[5] / 2;
    const int total = E + N;
    const int* src = edge;
    const int* dst = edge + E;
    float* out = (float*)d_out;

    const int NB = (N + BKT_MASK) >> BKT_SHIFT;       // 196 buckets
    const int ntile = (N + 63) / 64;                  // 782 (= nchunk)
    const int chunkE = (total + ntile - 1) / ntile;   // ~2112 edges/chunk

    // workspace (4B units): hb[N*C/2] | as[N] | ad[N] | row_start[N+2]
    // | packed[total] | csr[total] | Wf[8192] | colTot[256] | bucket_off[257]
    // | H[ntile*256]
    float* ws = (float*)d_ws;
    unsigned short* hb = (unsigned short*)ws;
    float* as = (float*)(hb + (size_t)N * C);
    float* ad = as + N;
    int* row_start = (int*)(ad + N);
    uint32* packed = (uint32*)(row_start + (N + 2));
    uint32* csr    = packed + total;
    uint32* Wf     = csr + total;
    int* colTot    = (int*)(Wf + 8192);
    int* bucket_off = colTot + 256;
    int* H          = bucket_off + 257;

    cvtw_kernel<<<32, 256, 0, stream>>>(W, Wf);
    gemm_hist_kernel<<<ntile, 256, 0, stream>>>(
        x, Wf, a_src, a_dst, hb, as, ad, N, dst, H, E, total, chunkE);
    scan_cols_kernel<<<256, 1024, 0, stream>>>(H, colTot, ntile);
    scan_off_kernel<<<1, 256, 0, stream>>>(colTot, bucket_off, total);
    bin_kernel<<<ntile, 256, 0, stream>>>(
        src, dst, bucket_off, H, packed, E, total, chunkE);
    build_kernel<<<NB, 1024, 0, stream>>>(packed, bucket_off, as, ad, row_start,
                                          csr, N, NB, total);
    gather_kernel<<<((N + 1) / 2 + 3) / 4, 256, 0, stream>>>(csr, row_start, hb, bias, out, N);
}

// Round 11
// 186.860 us; speedup vs baseline: 2.3425x; 1.0042x over previous
//
#include <hip/hip_runtime.h>
#include <hip/hip_fp16.h>

#define C 128
#define NEG_SLOPE 0.2f
#define SM_EPS 1e-16f
#define BKT_SHIFT 8            // 256 nodes per bucket
#define BKT_MASK 255
#define WP 136                 // LDS pitch (u16) for h-writeback slice

typedef unsigned int uint32;
typedef __attribute__((ext_vector_type(8))) short bf16x8;
typedef __attribute__((ext_vector_type(4))) float f32x4;

// ---- bf16 helpers (RNE) ----
static __device__ __forceinline__ unsigned short f2bf(float f) {
    uint32 u = __float_as_uint(f);
    uint32 r = 0x7FFFu + ((u >> 16) & 1u);
    return (unsigned short)((u + r) >> 16);
}
static __device__ __forceinline__ uint32 f2bf2(float lo, float hi) {
    return (uint32)f2bf(lo) | ((uint32)f2bf(hi) << 16);
}
// ---- f16 bit helpers ----
static __device__ __forceinline__ uint32 f2h(float f) {
    __half h = __float2half(f);
    return (uint32)*reinterpret_cast<unsigned short*>(&h);
}
static __device__ __forceinline__ float h2f(uint32 b) {
    unsigned short s = (unsigned short)(b & 0xffffu);
    __half h = *reinterpret_cast<__half*>(&s);
    return __half2float(h);
}

// ---- k0: W -> bf16 fragment-ordered ----
__global__ __launch_bounds__(256) void cvtw_kernel(const float* __restrict__ W,
                                                   uint32* __restrict__ Wf) {
    int gid = blockIdx.x * 256 + threadIdx.x;       // 0..8191
    int j2   = gid & 3;
    int lane = (gid >> 2) & 63;
    int tile = gid >> 8;                            // t*4+kk
    int t = tile >> 2, kk = tile & 3;
    int n = t * 16 + (lane & 15);
    int k = kk * 32 + (lane >> 4) * 8 + j2 * 2;
    Wf[gid] = f2bf2(W[k * C + n], W[(k + 1) * C + n]);
}

// ---- k1: MFMA GEMM + alpha reductions + bf16 h + per-chunk hist row ----
__global__ __launch_bounds__(256) void gemm_hist_kernel(
    const float* __restrict__ x, const uint32* __restrict__ Wf,
    const float* __restrict__ a_src, const float* __restrict__ a_dst,
    unsigned short* __restrict__ hb, float* __restrict__ as_out,
    float* __restrict__ ad_out, int N,
    const int* __restrict__ dst, int* __restrict__ H,
    int E, int total, int chunkE)
{
    __shared__ __align__(16) unsigned short slice[4][16 * WP];
    __shared__ int lhist[256];

    const int tid  = threadIdx.x;
    const int lane = tid & 63;
    const int w    = tid >> 6;
    const int row0 = blockIdx.x * 64;
    const int m16  = lane & 15;
    const int q    = lane >> 4;

    lhist[tid] = 0;

    const int row = row0 + w * 16 + m16;
    const bool rv = (row < N);
    const float* xr_p = x + (size_t)(rv ? row : 0) * C + q * 8;

    float4 xr[8];
    #pragma unroll
    for (int kk = 0; kk < 4; ++kk) {
        xr[kk * 2]     = rv ? *(const float4*)(xr_p + kk * 32)     : make_float4(0, 0, 0, 0);
        xr[kk * 2 + 1] = rv ? *(const float4*)(xr_p + kk * 32 + 4) : make_float4(0, 0, 0, 0);
    }

    f32x4 acc[8];
    const f32x4 zz = {0.f, 0.f, 0.f, 0.f};
    #pragma unroll
    for (int t = 0; t < 8; ++t) acc[t] = zz;

    #pragma unroll
    for (int kk = 0; kk < 4; ++kk) {
        union { bf16x8 v; uint32 u[4]; } au;
        float4 p0 = xr[kk * 2], p1 = xr[kk * 2 + 1];
        au.u[0] = f2bf2(p0.x, p0.y); au.u[1] = f2bf2(p0.z, p0.w);
        au.u[2] = f2bf2(p1.x, p1.y); au.u[3] = f2bf2(p1.z, p1.w);
        #pragma unroll
        for (int t = 0; t < 8; ++t) {
            bf16x8 b = *(const bf16x8*)&Wf[((t * 4 + kk) * 64 + lane) * 4];
            acc[t] = __builtin_amdgcn_mfma_f32_16x16x32_bf16(au.v, b, acc[t], 0, 0, 0);
        }
    }

    float ps[4] = {0.f, 0.f, 0.f, 0.f}, pd[4] = {0.f, 0.f, 0.f, 0.f};
    #pragma unroll
    for (int t = 0; t < 8; ++t) {
        float av = a_src[t * 16 + m16];
        float dv = a_dst[t * 16 + m16];
        #pragma unroll
        for (int r = 0; r < 4; ++r) {
            ps[r] += acc[t][r] * av;
            pd[r] += acc[t][r] * dv;
        }
    }
    #pragma unroll
    for (int r = 0; r < 4; ++r) {
        #pragma unroll
        for (int off = 1; off < 16; off <<= 1) {
            ps[r] += __shfl_xor(ps[r], off, 64);
            pd[r] += __shfl_xor(pd[r], off, 64);
        }
    }
    if (m16 == 0) {
        #pragma unroll
        for (int r = 0; r < 4; ++r) {
            int rr = row0 + w * 16 + q * 4 + r;
            if (rr < N) { as_out[rr] = ps[r]; ad_out[rr] = pd[r]; }
        }
    }

    #pragma unroll
    for (int t = 0; t < 8; ++t)
        #pragma unroll
        for (int r = 0; r < 4; ++r)
            slice[w][(q * 4 + r) * WP + t * 16 + m16] = f2bf(acc[t][r]);
    __syncthreads();
    #pragma unroll
    for (int it = 0; it < 4; ++it) {
        int r = it * 4 + q;
        int rr = row0 + w * 16 + r;
        if (rr < N) {
            bf16x8 v = *(const bf16x8*)&slice[w][r * WP + m16 * 8];
            *(bf16x8*)&hb[(size_t)rr * C + m16 * 8] = v;
        }
    }

    // per-chunk histogram (chunk = blockIdx), LDS-only, plain store to H row
    const int c = blockIdx.x;
    const int start = c * chunkE;
    const int end = min(start + chunkE, total);
    for (int i = start + tid; i < end; i += 256) {
        int d = (i < E) ? dst[i] : (i - E);
        atomicAdd(&lhist[d >> BKT_SHIFT], 1);
    }
    __syncthreads();
    H[c * 256 + tid] = lhist[tid];
}

// ---- k2: parallel column scan of H (one column per block) ----
__global__ __launch_bounds__(1024) void scan_cols_kernel(
    int* __restrict__ H, int* __restrict__ colTot, int nchunk)
{
    __shared__ int wt[16];
    const int tid  = threadIdx.x;
    const int lane = tid & 63;
    const int w    = tid >> 6;
    const int col  = blockIdx.x;
    int v = (tid < nchunk) ? H[tid * 256 + col] : 0;
    int x = v;
    #pragma unroll
    for (int o = 1; o < 64; o <<= 1) {
        int t = __shfl_up(x, o, 64);
        if (lane >= o) x += t;
    }
    if (lane == 63) wt[w] = x;
    __syncthreads();
    int wbase = 0;
    #pragma unroll
    for (int w2 = 0; w2 < 16; ++w2) wbase += (w2 < w) ? wt[w2] : 0;
    int e = wbase + x - v;
    if (tid < nchunk) H[tid * 256 + col] = e;
    if (tid == nchunk - 1) colTot[col] = e + v;
}

// ---- k3: bin, SINGLE-pass deterministic scatter (no global atomics) ----
// slot = scan(colTot)[b] + H[chunk][b] + LDS rank.
__global__ __launch_bounds__(256) void bin_kernel(
    const int* __restrict__ src, const int* __restrict__ dst,
    const int* __restrict__ colTot, const int* __restrict__ H,
    uint32* __restrict__ packed, int E, int total, int chunkE)
{
    __shared__ int lhist[256];
    __shared__ int base[256];
    __shared__ int wt[4];
    const int tid = threadIdx.x;
    const int lane = tid & 63;
    const int w = tid >> 6;
    const int c = blockIdx.x;
    const int start = c * chunkE;
    const int end = min(start + chunkE, total);

    // in-block exclusive scan of colTot -> per-bucket global base
    int v = colTot[tid];
    int x = v;
    #pragma unroll
    for (int o = 1; o < 64; o <<= 1) {
        int t = __shfl_up(x, o, 64);
        if (lane >= o) x += t;
    }
    if (lane == 63) wt[w] = x;
    lhist[tid] = 0;
    __syncthreads();
    int wbase = 0;
    #pragma unroll
    for (int w2 = 0; w2 < 4; ++w2) wbase += (w2 < w) ? wt[w2] : 0;
    base[tid] = (wbase + x - v) + H[c * 256 + tid];
    __syncthreads();

    for (int i = start + tid; i < end; i += 256) {
        int s = (i < E) ? src[i] : (i - E);
        int d = (i < E) ? dst[i] : (i - E);
        int b = d >> BKT_SHIFT;
        int pos = base[b] + atomicAdd(&lhist[b], 1);
        packed[pos] = ((uint32)s << BKT_SHIFT) | (uint32)(d & BKT_MASK);
    }
}

// ---- k4: build, per-bucket fine sort + fused e (boff from colTot scan) ----
__global__ __launch_bounds__(1024) void build_kernel(
    const uint32* __restrict__ packed, const int* __restrict__ colTot,
    const float* __restrict__ as, const float* __restrict__ ad,
    int* __restrict__ row_start, uint32* __restrict__ csr, int N, int NB, int total)
{
    __shared__ int cnt[256];
    __shared__ int cur[256];
    __shared__ float adl[256];
    __shared__ int wt[4];
    __shared__ int boff[257];
    const int tid = threadIdx.x;
    const int b = blockIdx.x;

    // phase 0: scan colTot -> boff (straight-line barriers, all 1024 thr)
    int v0 = 0, x0 = 0;
    if (tid < 256) {
        const int lane = tid & 63;
        v0 = colTot[tid]; x0 = v0;
        #pragma unroll
        for (int o = 1; o < 64; o <<= 1) {
            int t = __shfl_up(x0, o, 64);
            if (lane >= o) x0 += t;
        }
        if (lane == 63) wt[tid >> 6] = x0;
        cnt[tid] = 0;
        int g = (b << BKT_SHIFT) + tid;
        adl[tid] = (g < N) ? ad[g] : 0.f;
    }
    __syncthreads();
    if (tid < 256) {
        const int w = tid >> 6;
        int wbase = 0;
        #pragma unroll
        for (int w2 = 0; w2 < 4; ++w2) wbase += (w2 < w) ? wt[w2] : 0;
        boff[tid] = wbase + x0 - v0;
        if (tid == 0) boff[256] = total;
    }
    __syncthreads();

    const int off = boff[b];
    const int end = boff[b + 1];
    if (b == 0 && tid == 0) row_start[N] = total;

    for (int j = off + tid; j < end; j += 1024)
        atomicAdd(&cnt[packed[j] & BKT_MASK], 1);
    __syncthreads();

    int v2 = 0, x2 = 0;
    if (tid < 256) {
        const int lane = tid & 63;
        v2 = cnt[tid]; x2 = v2;
        #pragma unroll
        for (int o = 1; o < 64; o <<= 1) {
            int t = __shfl_up(x2, o, 64);
            if (lane >= o) x2 += t;
        }
        if (lane == 63) wt[tid >> 6] = x2;
    }
    __syncthreads();
    if (tid < 256) {
        const int w = tid >> 6;
        int wbase = 0;
        #pragma unroll
        for (int w2 = 0; w2 < 4; ++w2) wbase += (w2 < w) ? wt[w2] : 0;
        int excl = wbase + x2 - v2;
        int g = (b << BKT_SHIFT) + tid;
        if (g < N) row_start[g] = off + excl;
        cur[tid] = excl;
    }
    __syncthreads();

    for (int j = off + tid; j < end; j += 1024) {
        uint32 p = packed[j];
        int l = (int)(p & BKT_MASK);
        int s = (int)(p >> BKT_SHIFT);
        float e = as[s] + adl[l];
        e = (e > 0.f) ? e : NEG_SLOPE * e;
        int pos = atomicAdd(&cur[l], 1);
        csr[off + pos] = ((uint32)s << 16) | f2h(e);
    }
}

// ---- full-wave fallback for deg>64 nodes ----
static __device__ __forceinline__ void gather_node_fw(
    int d, const uint32* __restrict__ csr, const int* __restrict__ row_start,
    const unsigned short* __restrict__ hb, const float* __restrict__ bias,
    float* __restrict__ out, int lane)
{
    const int beg = row_start[d];
    const int deg = row_start[d + 1] - beg;
    const int c2 = lane << 1;
    float a0 = 0.f, a1 = 0.f;
    float m = -INFINITY;
    for (int t = lane; t < deg; t += 64) m = fmaxf(m, h2f(csr[beg + t]));
    #pragma unroll
    for (int off = 32; off > 0; off >>= 1) m = fmaxf(m, __shfl_xor(m, off, 64));
    float ssum = 0.f;
    for (int t = lane; t < deg; t += 64) ssum += __expf(h2f(csr[beg + t]) - m);
    #pragma unroll
    for (int off = 32; off > 0; off >>= 1) ssum += __shfl_xor(ssum, off, 64);
    float inv = 1.f / (ssum + SM_EPS);
    for (int t0 = 0; t0 < deg; t0 += 64) {
        int nc = min(64, deg - t0);
        uint32 ent = (lane < nc) ? csr[beg + t0 + lane] : 0xFC00u;
        float wl = (lane < nc) ? __expf(h2f(ent) - m) * inv : 0.f;
        uint32 bc = (ent & 0xffff0000u) | f2h(wl);
        for (int t = 0; t < nc; ++t) {
            uint32 b0 = (uint32)__shfl((int)bc, t, 64);
            uint32 u0 = *(const uint32*)&hb[(size_t)(b0 >> 16) * C + c2];
            float w0 = h2f(b0);
            a0 += __uint_as_float(u0 << 16) * w0;
            a1 += __uint_as_float(u0 & 0xffff0000u) * w0;
        }
    }
    float2 b2 = *(const float2*)&bias[c2];
    a0 = fmaxf(a0 + b2.x, 0.f);
    a1 = fmaxf(a1 + b2.y, 0.f);
    *(float2*)&out[(size_t)d * C + c2] = make_float2(a0, a1);
}

// per-edge unpack+FMA on a loaded uint4 row fragment (8 bf16 channels)
#define ACC8(r, wgt)                                           \
    {                                                          \
        a0 += __uint_as_float((r).x << 16)         * (wgt);    \
        a1 += __uint_as_float((r).x & 0xffff0000u) * (wgt);    \
        a2 += __uint_as_float((r).y << 16)         * (wgt);    \
        a3 += __uint_as_float((r).y & 0xffff0000u) * (wgt);    \
        a4 += __uint_as_float((r).z << 16)         * (wgt);    \
        a5 += __uint_as_float((r).z & 0xffff0000u) * (wgt);    \
        a6 += __uint_as_float((r).w << 16)         * (wgt);    \
        a7 += __uint_as_float((r).w & 0xffff0000u) * (wgt);    \
    }

// ---- k5: quarter-wave gather: 4 dst nodes per wave, 8 ch/lane, 16B loads ----
__global__ __launch_bounds__(256) void gather_kernel(
    const uint32* __restrict__ csr, const int* __restrict__ row_start,
    const unsigned short* __restrict__ hb, const float* __restrict__ bias,
    float* __restrict__ out, int N)
{
    // [wave][quarter][entry], entry stride padded to 66 to stagger quarter banks
    __shared__ __align__(16) uint2 lent[4][4][66];   // 8.25 KB
    const int w    = threadIdx.x >> 6;
    const int lane = threadIdx.x & 63;
    const int qt   = lane >> 4;            // quarter 0..3
    const int ql   = lane & 15;
    const int quad = blockIdx.x * 4 + w;
    const int d0 = quad * 4;
    if (d0 >= N) return;                   // no barriers below: safe
    const int d = d0 + qt;
    const bool valid = (d < N);

    int beg = 0, deg = 0;
    if (valid) { beg = row_start[d]; deg = row_start[d + 1] - beg; }

    int wdeg = deg;
    #pragma unroll
    for (int off = 32; off > 0; off >>= 1) wdeg = max(wdeg, __shfl_xor(wdeg, off, 64));

    if (wdeg > 64) {
        #pragma unroll
        for (int k = 0; k < 4; ++k)
            if (d0 + k < N) gather_node_fw(d0 + k, csr, row_start, hb, bias, out, lane);
        return;
    }

    uint32 ent0 = (ql < deg) ? csr[beg + ql] : 0xFC00u;
    uint32 ent1 = (16 + ql < deg) ? csr[beg + 16 + ql] : 0xFC00u;
    uint32 ent2 = (32 + ql < deg) ? csr[beg + 32 + ql] : 0xFC00u;
    uint32 ent3 = (48 + ql < deg) ? csr[beg + 48 + ql] : 0xFC00u;
    float e0 = h2f(ent0), e1 = h2f(ent1), e2 = h2f(ent2), e3 = h2f(ent3);
    float m = fmaxf(fmaxf(e0, e1), fmaxf(e2, e3));
    #pragma unroll
    for (int off = 8; off > 0; off >>= 1) m = fmaxf(m, __shfl_xor(m, off, 64));
    float p0 = (ql < deg) ? __expf(e0 - m) : 0.f;
    float p1 = (16 + ql < deg) ? __expf(e1 - m) : 0.f;
    float p2 = (32 + ql < deg) ? __expf(e2 - m) : 0.f;
    float p3 = (48 + ql < deg) ? __expf(e3 - m) : 0.f;
    float ssum = (p0 + p1) + (p2 + p3);
    #pragma unroll
    for (int off = 8; off > 0; off >>= 1) ssum += __shfl_xor(ssum, off, 64);
    const float inv = 1.f / (ssum + SM_EPS);

    // stage {row byte offset = src*256, f32 weight} — wave-synchronous LDS
    uint2* lq = &lent[w][qt][0];
    lq[ql]      = make_uint2((ent0 & 0xffff0000u) >> 8, __float_as_uint(p0 * inv));
    lq[16 + ql] = make_uint2((ent1 & 0xffff0000u) >> 8, __float_as_uint(p1 * inv));
    lq[32 + ql] = make_uint2((ent2 & 0xffff0000u) >> 8, __float_as_uint(p2 * inv));
    lq[48 + ql] = make_uint2((ent3 & 0xffff0000u) >> 8, __float_as_uint(p3 * inv));
    __builtin_amdgcn_wave_barrier();       // keep writes before reads (same wave)

    const uint32 cb = (uint32)(ql << 4);   // this lane's 16-byte channel slice
    const char* hbB = (const char*)hb;
    float a0 = 0.f, a1 = 0.f, a2 = 0.f, a3 = 0.f;
    float a4 = 0.f, a5 = 0.f, a6 = 0.f, a7 = 0.f;

    int t = 0;
    for (; t + 8 <= deg; t += 8) {
        uint4 q0 = *(const uint4*)(lq + t);
        uint4 q1 = *(const uint4*)(lq + t + 2);
        uint4 q2 = *(const uint4*)(lq + t + 4);
        uint4 q3 = *(const uint4*)(lq + t + 6);
        uint4 r0 = *(const uint4*)(hbB + (q0.x + cb));
        uint4 r1 = *(const uint4*)(hbB + (q0.z + cb));
        uint4 r2 = *(const uint4*)(hbB + (q1.x + cb));
        uint4 r3 = *(const uint4*)(hbB + (q1.z + cb));
        uint4 r4 = *(const uint4*)(hbB + (q2.x + cb));
        uint4 r5 = *(const uint4*)(hbB + (q2.z + cb));
        uint4 r6 = *(const uint4*)(hbB + (q3.x + cb));
        uint4 r7 = *(const uint4*)(hbB + (q3.z + cb));
        float w0 = __uint_as_float(q0.y), w1 = __uint_as_float(q0.w);
        float w2 = __uint_as_float(q1.y), w3 = __uint_as_float(q1.w);
        float w4 = __uint_as_float(q2.y), w5 = __uint_as_float(q2.w);
        float w6 = __uint_as_float(q3.y), w7 = __uint_as_float(q3.w);
        ACC8(r0, w0) ACC8(r1, w1) ACC8(r2, w2) ACC8(r3, w3)
        ACC8(r4, w4) ACC8(r5, w5) ACC8(r6, w6) ACC8(r7, w7)
    }
    for (; t < deg; ++t) {
        uint2 qv = lq[t];
        uint4 r = *(const uint4*)(hbB + (qv.x + cb));
        float wt2 = __uint_as_float(qv.y);
        ACC8(r, wt2)
    }

    if (valid) {
        const int c8 = ql << 3;
        float4 b0 = *(const float4*)&bias[c8];
        float4 b1 = *(const float4*)&bias[c8 + 4];
        float4 o0, o1;
        o0.x = fmaxf(a0 + b0.x, 0.f);
        o0.y = fmaxf(a1 + b0.y, 0.f);
        o0.z = fmaxf(a2 + b0.z, 0.f);
        o0.w = fmaxf(a3 + b0.w, 0.f);
        o1.x = fmaxf(a4 + b1.x, 0.f);
        o1.y = fmaxf(a5 + b1.y, 0.f);
        o1.z = fmaxf(a6 + b1.z, 0.f);
        o1.w = fmaxf(a7 + b1.w, 0.f);
        *(float4*)&out[(size_t)d * C + c8] = o0;
        *(float4*)&out[(size_t)d * C + c8 + 4] = o1;
    }
}

extern "C" void kernel_launch(void* const* d_in, const int* in_sizes, int n_in,
                              void* d_out, int out_size, void* d_ws, size_t ws_size,
                              hipStream_t stream) {
    const float* x     = (const float*)d_in[0];
    const float* W     = (const float*)d_in[1];
    const float* a_src = (const float*)d_in[2];
    const float* a_dst = (const float*)d_in[3];
    const float* bias  = (const float*)d_in[4];
    const int*   edge  = (const int*)d_in[5];

    const int N = in_sizes[0] / C;
    const int E = in_sizes[5] / 2;
    const int total = E + N;
    const int* src = edge;
    const int* dst = edge + E;
    float* out = (float*)d_out;

    const int NB = (N + BKT_MASK) >> BKT_SHIFT;       // 196 buckets
    const int ntile = (N + 63) / 64;                  // 782 (= nchunk)
    const int chunkE = (total + ntile - 1) / ntile;   // ~2112 edges/chunk

    // workspace (4B units): hb[N*C/2] | as[N] | ad[N] | row_start[N+2]
    // | packed[total] | csr[total] | Wf[8192] | colTot[256] | H[ntile*256]
    float* ws = (float*)d_ws;
    unsigned short* hb = (unsigned short*)ws;
    float* as = (float*)(hb + (size_t)N * C);
    float* ad = as + N;
    int* row_start = (int*)(ad + N);
    uint32* packed = (uint32*)(row_start + (N + 2));
    uint32* csr    = packed + total;
    uint32* Wf     = csr + total;
    int* colTot    = (int*)(Wf + 8192);
    int* H         = colTot + 256;

    cvtw_kernel<<<32, 256, 0, stream>>>(W, Wf);
    gemm_hist_kernel<<<ntile, 256, 0, stream>>>(
        x, Wf, a_src, a_dst, hb, as, ad, N, dst, H, E, total, chunkE);
    scan_cols_kernel<<<256, 1024, 0, stream>>>(H, colTot, ntile);
    bin_kernel<<<ntile, 256, 0, stream>>>(
        src, dst, colTot, H, packed, E, total, chunkE);
    build_kernel<<<NB, 1024, 0, stream>>>(packed, colTot, as, ad, row_start,
                                          csr, N, NB, total);
    gather_kernel<<<((N + 3) / 4 + 3) / 4, 256, 0, stream>>>(csr, row_start, hb, bias, out, N);
}

// Round 12
// 181.578 us; speedup vs baseline: 2.4106x; 1.0291x over previous
//
#include <hip/hip_runtime.h>
#include <hip/hip_fp16.h>

#define C 128
#define NEG_SLOPE 0.2f
#define SM_EPS 1e-16f
#define BKT_SHIFT 8            // 256 nodes per bucket
#define BKT_MASK 255
#define WP 136                 // LDS pitch (u16) for h-writeback slice

typedef unsigned int uint32;
typedef __attribute__((ext_vector_type(8))) short bf16x8;
typedef __attribute__((ext_vector_type(4))) float f32x4;

// ---- bf16 helpers (RNE) ----
static __device__ __forceinline__ unsigned short f2bf(float f) {
    uint32 u = __float_as_uint(f);
    uint32 r = 0x7FFFu + ((u >> 16) & 1u);
    return (unsigned short)((u + r) >> 16);
}
static __device__ __forceinline__ uint32 f2bf2(float lo, float hi) {
    return (uint32)f2bf(lo) | ((uint32)f2bf(hi) << 16);
}
// ---- f16 bit helpers ----
static __device__ __forceinline__ uint32 f2h(float f) {
    __half h = __float2half(f);
    return (uint32)*reinterpret_cast<unsigned short*>(&h);
}
static __device__ __forceinline__ float h2f(uint32 b) {
    unsigned short s = (unsigned short)(b & 0xffffu);
    __half h = *reinterpret_cast<__half*>(&s);
    return __half2float(h);
}

// ---- k1: W -> bf16 fragment-ordered + per-chunk bucket histogram ----
__global__ __launch_bounds__(256) void cvtw_hist_kernel(
    const float* __restrict__ W, uint32* __restrict__ Wf,
    const int* __restrict__ dst, int* __restrict__ H,
    int E, int total, int nchunk, int chunkE)
{
    __shared__ int lhist[256];
    const int tid = threadIdx.x;
    lhist[tid] = 0;
    const int gid = blockIdx.x * 256 + tid;
    if (gid < 8192) {                              // blocks 0..31: W conversion
        int j2   = gid & 3;
        int lane = (gid >> 2) & 63;
        int tile = gid >> 8;                        // t*4+kk
        int t = tile >> 2, kk = tile & 3;
        int n = t * 16 + (lane & 15);
        int k = kk * 32 + (lane >> 4) * 8 + j2 * 2;
        Wf[gid] = f2bf2(W[k * C + n], W[(k + 1) * C + n]);
    }
    const int c = blockIdx.x;
    if (c >= nchunk) return;
    __syncthreads();
    const int start = c * chunkE;
    const int end = min(start + chunkE, total);
    for (int i = start + tid; i < end; i += 256) {
        int d = (i < E) ? dst[i] : (i - E);
        atomicAdd(&lhist[d >> BKT_SHIFT], 1);
    }
    __syncthreads();
    H[c * 256 + tid] = lhist[tid];
}

// ---- k2: parallel column scan of H (one column per block) ----
__global__ __launch_bounds__(1024) void scan_cols_kernel(
    int* __restrict__ H, int* __restrict__ colTot, int nchunk)
{
    __shared__ int wt[16];
    const int tid  = threadIdx.x;
    const int lane = tid & 63;
    const int w    = tid >> 6;
    const int col  = blockIdx.x;
    int v = (tid < nchunk) ? H[tid * 256 + col] : 0;
    int x = v;
    #pragma unroll
    for (int o = 1; o < 64; o <<= 1) {
        int t = __shfl_up(x, o, 64);
        if (lane >= o) x += t;
    }
    if (lane == 63) wt[w] = x;
    __syncthreads();
    int wbase = 0;
    #pragma unroll
    for (int w2 = 0; w2 < 16; ++w2) wbase += (w2 < w) ? wt[w2] : 0;
    int e = wbase + x - v;
    if (tid < nchunk) H[tid * 256 + col] = e;
    if (tid == nchunk - 1) colTot[col] = e + v;
}

// ---- k3: role-split — GEMM tiles (blocks < ntile) || bin chunks (rest) ----
__global__ __launch_bounds__(256) void gemm_bin_kernel(
    const float* __restrict__ x, const uint32* __restrict__ Wf,
    const float* __restrict__ a_src, const float* __restrict__ a_dst,
    unsigned short* __restrict__ hb, float* __restrict__ as_out,
    float* __restrict__ ad_out, int N,
    const int* __restrict__ src, const int* __restrict__ dst,
    const int* __restrict__ colTot, const int* __restrict__ H,
    uint32* __restrict__ packed, int E, int total, int ntile, int chunkE)
{
    __shared__ __align__(16) unsigned short slice[4][16 * WP];
    __shared__ int lhist[256];
    __shared__ int base[256];
    __shared__ int wt[4];

    const int tid  = threadIdx.x;
    const int lane = tid & 63;
    const int w    = tid >> 6;

    if (blockIdx.x < (unsigned)ntile) {
        // ================= GEMM role =================
        const int row0 = blockIdx.x * 64;
        const int m16  = lane & 15;
        const int q    = lane >> 4;

        const int row = row0 + w * 16 + m16;
        const bool rv = (row < N);
        const float* xr_p = x + (size_t)(rv ? row : 0) * C + q * 8;

        float4 xr[8];
        #pragma unroll
        for (int kk = 0; kk < 4; ++kk) {
            xr[kk * 2]     = rv ? *(const float4*)(xr_p + kk * 32)     : make_float4(0, 0, 0, 0);
            xr[kk * 2 + 1] = rv ? *(const float4*)(xr_p + kk * 32 + 4) : make_float4(0, 0, 0, 0);
        }

        f32x4 acc[8];
        const f32x4 zz = {0.f, 0.f, 0.f, 0.f};
        #pragma unroll
        for (int t = 0; t < 8; ++t) acc[t] = zz;

        #pragma unroll
        for (int kk = 0; kk < 4; ++kk) {
            union { bf16x8 v; uint32 u[4]; } au;
            float4 p0 = xr[kk * 2], p1 = xr[kk * 2 + 1];
            au.u[0] = f2bf2(p0.x, p0.y); au.u[1] = f2bf2(p0.z, p0.w);
            au.u[2] = f2bf2(p1.x, p1.y); au.u[3] = f2bf2(p1.z, p1.w);
            #pragma unroll
            for (int t = 0; t < 8; ++t) {
                bf16x8 b = *(const bf16x8*)&Wf[((t * 4 + kk) * 64 + lane) * 4];
                acc[t] = __builtin_amdgcn_mfma_f32_16x16x32_bf16(au.v, b, acc[t], 0, 0, 0);
            }
        }

        float ps[4] = {0.f, 0.f, 0.f, 0.f}, pd[4] = {0.f, 0.f, 0.f, 0.f};
        #pragma unroll
        for (int t = 0; t < 8; ++t) {
            float av = a_src[t * 16 + m16];
            float dv = a_dst[t * 16 + m16];
            #pragma unroll
            for (int r = 0; r < 4; ++r) {
                ps[r] += acc[t][r] * av;
                pd[r] += acc[t][r] * dv;
            }
        }
        #pragma unroll
        for (int r = 0; r < 4; ++r) {
            #pragma unroll
            for (int off = 1; off < 16; off <<= 1) {
                ps[r] += __shfl_xor(ps[r], off, 64);
                pd[r] += __shfl_xor(pd[r], off, 64);
            }
        }
        if (m16 == 0) {
            #pragma unroll
            for (int r = 0; r < 4; ++r) {
                int rr = row0 + w * 16 + q * 4 + r;
                if (rr < N) { as_out[rr] = ps[r]; ad_out[rr] = pd[r]; }
            }
        }

        #pragma unroll
        for (int t = 0; t < 8; ++t)
            #pragma unroll
            for (int r = 0; r < 4; ++r)
                slice[w][(q * 4 + r) * WP + t * 16 + m16] = f2bf(acc[t][r]);
        __syncthreads();
        #pragma unroll
        for (int it = 0; it < 4; ++it) {
            int r = it * 4 + q;
            int rr = row0 + w * 16 + r;
            if (rr < N) {
                bf16x8 v = *(const bf16x8*)&slice[w][r * WP + m16 * 8];
                *(bf16x8*)&hb[(size_t)rr * C + m16 * 8] = v;
            }
        }
    } else {
        // ================= bin role (single-pass deterministic scatter) ====
        const int c = blockIdx.x - ntile;
        const int start = c * chunkE;
        const int end = min(start + chunkE, total);

        // in-block exclusive scan of colTot -> per-bucket global base
        int v = colTot[tid];
        int xx = v;
        #pragma unroll
        for (int o = 1; o < 64; o <<= 1) {
            int t = __shfl_up(xx, o, 64);
            if (lane >= o) xx += t;
        }
        if (lane == 63) wt[w] = xx;
        lhist[tid] = 0;
        __syncthreads();
        int wbase = 0;
        #pragma unroll
        for (int w2 = 0; w2 < 4; ++w2) wbase += (w2 < w) ? wt[w2] : 0;
        base[tid] = (wbase + xx - v) + H[c * 256 + tid];
        __syncthreads();

        for (int i = start + tid; i < end; i += 256) {
            int s = (i < E) ? src[i] : (i - E);
            int d = (i < E) ? dst[i] : (i - E);
            int b = d >> BKT_SHIFT;
            int pos = base[b] + atomicAdd(&lhist[b], 1);
            packed[pos] = ((uint32)s << BKT_SHIFT) | (uint32)(d & BKT_MASK);
        }
    }
}

// ---- k4: build, per-bucket fine sort + fused e (boff from colTot scan) ----
__global__ __launch_bounds__(1024) void build_kernel(
    const uint32* __restrict__ packed, const int* __restrict__ colTot,
    const float* __restrict__ as, const float* __restrict__ ad,
    int* __restrict__ row_start, uint32* __restrict__ csr, int N, int NB, int total)
{
    __shared__ int cnt[256];
    __shared__ int cur[256];
    __shared__ float adl[256];
    __shared__ int wt[4];
    __shared__ int boff[257];
    const int tid = threadIdx.x;
    const int b = blockIdx.x;

    // phase 0: scan colTot -> boff (straight-line barriers, all 1024 thr)
    int v0 = 0, x0 = 0;
    if (tid < 256) {
        const int lane = tid & 63;
        v0 = colTot[tid]; x0 = v0;
        #pragma unroll
        for (int o = 1; o < 64; o <<= 1) {
            int t = __shfl_up(x0, o, 64);
            if (lane >= o) x0 += t;
        }
        if (lane == 63) wt[tid >> 6] = x0;
        cnt[tid] = 0;
        int g = (b << BKT_SHIFT) + tid;
        adl[tid] = (g < N) ? ad[g] : 0.f;
    }
    __syncthreads();
    if (tid < 256) {
        const int w = tid >> 6;
        int wbase = 0;
        #pragma unroll
        for (int w2 = 0; w2 < 4; ++w2) wbase += (w2 < w) ? wt[w2] : 0;
        boff[tid] = wbase + x0 - v0;
        if (tid == 0) boff[256] = total;
    }
    __syncthreads();

    const int off = boff[b];
    const int end = boff[b + 1];
    if (b == 0 && tid == 0) row_start[N] = total;

    for (int j = off + tid; j < end; j += 1024)
        atomicAdd(&cnt[packed[j] & BKT_MASK], 1);
    __syncthreads();

    int v2 = 0, x2 = 0;
    if (tid < 256) {
        const int lane = tid & 63;
        v2 = cnt[tid]; x2 = v2;
        #pragma unroll
        for (int o = 1; o < 64; o <<= 1) {
            int t = __shfl_up(x2, o, 64);
            if (lane >= o) x2 += t;
        }
        if (lane == 63) wt[tid >> 6] = x2;
    }
    __syncthreads();
    if (tid < 256) {
        const int w = tid >> 6;
        int wbase = 0;
        #pragma unroll
        for (int w2 = 0; w2 < 4; ++w2) wbase += (w2 < w) ? wt[w2] : 0;
        int excl = wbase + x2 - v2;
        int g = (b << BKT_SHIFT) + tid;
        if (g < N) row_start[g] = off + excl;
        cur[tid] = excl;
    }
    __syncthreads();

    for (int j = off + tid; j < end; j += 1024) {
        uint32 p = packed[j];
        int l = (int)(p & BKT_MASK);
        int s = (int)(p >> BKT_SHIFT);
        float e = as[s] + adl[l];
        e = (e > 0.f) ? e : NEG_SLOPE * e;
        int pos = atomicAdd(&cur[l], 1);
        csr[off + pos] = ((uint32)s << 16) | f2h(e);
    }
}

// ---- full-wave fallback for deg>64 nodes ----
static __device__ __forceinline__ void gather_node_fw(
    int d, const uint32* __restrict__ csr, const int* __restrict__ row_start,
    const unsigned short* __restrict__ hb, const float* __restrict__ bias,
    float* __restrict__ out, int lane)
{
    const int beg = row_start[d];
    const int deg = row_start[d + 1] - beg;
    const int c2 = lane << 1;
    float a0 = 0.f, a1 = 0.f;
    float m = -INFINITY;
    for (int t = lane; t < deg; t += 64) m = fmaxf(m, h2f(csr[beg + t]));
    #pragma unroll
    for (int off = 32; off > 0; off >>= 1) m = fmaxf(m, __shfl_xor(m, off, 64));
    float ssum = 0.f;
    for (int t = lane; t < deg; t += 64) ssum += __expf(h2f(csr[beg + t]) - m);
    #pragma unroll
    for (int off = 32; off > 0; off >>= 1) ssum += __shfl_xor(ssum, off, 64);
    float inv = 1.f / (ssum + SM_EPS);
    for (int t0 = 0; t0 < deg; t0 += 64) {
        int nc = min(64, deg - t0);
        uint32 ent = (lane < nc) ? csr[beg + t0 + lane] : 0xFC00u;
        float wl = (lane < nc) ? __expf(h2f(ent) - m) * inv : 0.f;
        uint32 bc = (ent & 0xffff0000u) | f2h(wl);
        for (int t = 0; t < nc; ++t) {
            uint32 b0 = (uint32)__shfl((int)bc, t, 64);
            uint32 u0 = *(const uint32*)&hb[(size_t)(b0 >> 16) * C + c2];
            float w0 = h2f(b0);
            a0 += __uint_as_float(u0 << 16) * w0;
            a1 += __uint_as_float(u0 & 0xffff0000u) * w0;
        }
    }
    float2 b2 = *(const float2*)&bias[c2];
    a0 = fmaxf(a0 + b2.x, 0.f);
    a1 = fmaxf(a1 + b2.y, 0.f);
    *(float2*)&out[(size_t)d * C + c2] = make_float2(a0, a1);
}

// per-edge unpack+FMA on a loaded uint2 row fragment (4 bf16 channels)
#define ACC4(r, wgt)                                           \
    {                                                          \
        a0 += __uint_as_float((r).x << 16)         * (wgt);    \
        a1 += __uint_as_float((r).x & 0xffff0000u) * (wgt);    \
        a2 += __uint_as_float((r).y << 16)         * (wgt);    \
        a3 += __uint_as_float((r).y & 0xffff0000u) * (wgt);    \
    }

// ---- k5: half-wave gather: 2 dst nodes per wave, 4 ch/lane, MLP=8 ----
__global__ __launch_bounds__(256) void gather_kernel(
    const uint32* __restrict__ csr, const int* __restrict__ row_start,
    const unsigned short* __restrict__ hb, const float* __restrict__ bias,
    float* __restrict__ out, int N)
{
    __shared__ __align__(16) uint2 lent[4][2][64];   // 4 KB: per-wave, per-half
    const int w    = threadIdx.x >> 6;
    const int lane = threadIdx.x & 63;
    const int half = lane >> 5;
    const int hl   = lane & 31;
    const int pair = blockIdx.x * 4 + w;
    const int d0 = pair * 2;
    if (d0 >= N) return;                    // no barriers below: safe
    const int d = d0 + half;
    const bool valid = (d < N);

    int beg = 0, deg = 0;
    if (valid) { beg = row_start[d]; deg = row_start[d + 1] - beg; }

    int wdeg = deg;
    #pragma unroll
    for (int off = 32; off > 0; off >>= 1) wdeg = max(wdeg, __shfl_xor(wdeg, off, 64));

    if (wdeg > 64) {
        gather_node_fw(d0, csr, row_start, hb, bias, out, lane);
        if (d0 + 1 < N) gather_node_fw(d0 + 1, csr, row_start, hb, bias, out, lane);
        return;
    }

    uint32 ent0 = (hl < deg) ? csr[beg + hl] : 0xFC00u;
    uint32 ent1 = (32 + hl < deg) ? csr[beg + 32 + hl] : 0xFC00u;
    float e0 = h2f(ent0), e1 = h2f(ent1);
    float m = fmaxf(e0, e1);
    #pragma unroll
    for (int off = 16; off > 0; off >>= 1) m = fmaxf(m, __shfl_xor(m, off, 64));
    float p0 = (hl < deg) ? __expf(e0 - m) : 0.f;
    float p1 = (32 + hl < deg) ? __expf(e1 - m) : 0.f;
    float ssum = p0 + p1;
    #pragma unroll
    for (int off = 16; off > 0; off >>= 1) ssum += __shfl_xor(ssum, off, 64);
    const float inv = 1.f / (ssum + SM_EPS);

    // stage {row byte offset = src*256, f32 weight} — wave-synchronous LDS
    lent[w][half][hl]      = make_uint2((ent0 & 0xffff0000u) >> 8, __float_as_uint(p0 * inv));
    lent[w][half][32 + hl] = make_uint2((ent1 & 0xffff0000u) >> 8, __float_as_uint(p1 * inv));
    __builtin_amdgcn_wave_barrier();        // keep writes before reads (same wave)

    const uint32 cb = (uint32)(hl << 3);    // this lane's channel byte offset
    const char* hbB = (const char*)hb;
    const uint2* lp = &lent[w][half][0];
    float a0 = 0.f, a1 = 0.f, a2 = 0.f, a3 = 0.f;

    int t = 0;
    for (; t + 8 <= deg; t += 8) {
        uint4 q0 = *(const uint4*)(lp + t);
        uint4 q1 = *(const uint4*)(lp + t + 2);
        uint4 q2 = *(const uint4*)(lp + t + 4);
        uint4 q3 = *(const uint4*)(lp + t + 6);
        uint2 r0 = *(const uint2*)(hbB + (q0.x + cb));
        uint2 r1 = *(const uint2*)(hbB + (q0.z + cb));
        uint2 r2 = *(const uint2*)(hbB + (q1.x + cb));
        uint2 r3 = *(const uint2*)(hbB + (q1.z + cb));
        uint2 r4 = *(const uint2*)(hbB + (q2.x + cb));
        uint2 r5 = *(const uint2*)(hbB + (q2.z + cb));
        uint2 r6 = *(const uint2*)(hbB + (q3.x + cb));
        uint2 r7 = *(const uint2*)(hbB + (q3.z + cb));
        float w0 = __uint_as_float(q0.y), w1 = __uint_as_float(q0.w);
        float w2 = __uint_as_float(q1.y), w3 = __uint_as_float(q1.w);
        float w4 = __uint_as_float(q2.y), w5 = __uint_as_float(q2.w);
        float w6 = __uint_as_float(q3.y), w7 = __uint_as_float(q3.w);
        ACC4(r0, w0) ACC4(r1, w1) ACC4(r2, w2) ACC4(r3, w3)
        ACC4(r4, w4) ACC4(r5, w5) ACC4(r6, w6) ACC4(r7, w7)
    }
    for (; t < deg; ++t) {
        uint2 q = lp[t];
        uint2 r = *(const uint2*)(hbB + (q.x + cb));
        float wt = __uint_as_float(q.y);
        ACC4(r, wt)
    }

    if (valid) {
        const int c4 = hl << 2;
        float4 bb = *(const float4*)&bias[c4];
        float4 o;
        o.x = fmaxf(a0 + bb.x, 0.f);
        o.y = fmaxf(a1 + bb.y, 0.f);
        o.z = fmaxf(a2 + bb.z, 0.f);
        o.w = fmaxf(a3 + bb.w, 0.f);
        *(float4*)&out[(size_t)d * C + c4] = o;
    }
}

extern "C" void kernel_launch(void* const* d_in, const int* in_sizes, int n_in,
                              void* d_out, int out_size, void* d_ws, size_t ws_size,
                              hipStream_t stream) {
    const float* x     = (const float*)d_in[0];
    const float* W     = (const float*)d_in[1];
    const float* a_src = (const float*)d_in[2];
    const float* a_dst = (const float*)d_in[3];
    const float* bias  = (const float*)d_in[4];
    const int*   edge  = (const int*)d_in[5];

    const int N = in_sizes[0] / C;
    const int E = in_sizes[5] / 2;
    const int total = E + N;
    const int* src = edge;
    const int* dst = edge + E;
    float* out = (float*)d_out;

    const int NB = (N + BKT_MASK) >> BKT_SHIFT;       // 196 buckets
    const int ntile = (N + 63) / 64;                  // 782 (= nchunk)
    const int chunkE = (total + ntile - 1) / ntile;   // ~2112 edges/chunk

    // workspace (4B units): hb[N*C/2] | as[N] | ad[N] | row_start[N+2]
    // | packed[total] | csr[total] | Wf[8192] | colTot[256] | H[ntile*256]
    float* ws = (float*)d_ws;
    unsigned short* hb = (unsigned short*)ws;
    float* as = (float*)(hb + (size_t)N * C);
    float* ad = as + N;
    int* row_start = (int*)(ad + N);
    uint32* packed = (uint32*)(row_start + (N + 2));
    uint32* csr    = packed + total;
    uint32* Wf     = csr + total;
    int* colTot    = (int*)(Wf + 8192);
    int* H         = colTot + 256;

    const int grid1 = (ntile > 32) ? ntile : 32;

    cvtw_hist_kernel<<<grid1, 256, 0, stream>>>(W, Wf, dst, H, E, total, ntile, chunkE);
    scan_cols_kernel<<<256, 1024, 0, stream>>>(H, colTot, ntile);
    gemm_bin_kernel<<<2 * ntile, 256, 0, stream>>>(
        x, Wf, a_src, a_dst, hb, as, ad, N, src, dst,
        colTot, H, packed, E, total, ntile, chunkE);
    build_kernel<<<NB, 1024, 0, stream>>>(packed, colTot, as, ad, row_start,
                                          csr, N, NB, total);
    gather_kernel<<<((N + 1) / 2 + 3) / 4, 256, 0, stream>>>(csr, row_start, hb, bias, out, N);
}